// Round 11
// baseline (259.357 us; speedup 1.0000x reference)
//
#include <hip/hip_runtime.h>
#include <stdint.h>

#define UNITS 64
#define UU 4096          // UNITS*UNITS
#define NG 50
#define NSLOT 51         // 50 gaussians + 1 bias slot
#define GAMMA_C 10.0f
#define STEP_C (30.0f / 49.0f)
#define NWIN 4           // gaussian window width (centers lo..lo+3)
#define NBKT 47          // lo in [0, 46]

typedef __attribute__((ext_vector_type(8))) short bf16x8;
typedef __attribute__((ext_vector_type(4))) float f32x4;

__device__ __forceinline__ float bfu(uint16_t v) { return __uint_as_float(((uint32_t)v) << 16); }
__device__ __forceinline__ uint16_t f2bf(float x) {
  uint32_t u = __float_as_uint(x);
  u += 0x7fffu + ((u >> 16) & 1u);           // RNE to bf16
  return (uint16_t)(u >> 16);
}
__device__ __forceinline__ uint32_t pk_bf16(float lo, float hi) {
  uint32_t r;
  asm("v_cvt_pk_bf16_f32 %0, %1, %2" : "=v"(r) : "v"(lo), "v"(hi));
  return r;
}
__device__ __forceinline__ int lo_of(float d) {
  int lo = (int)floorf(d * (1.0f / STEP_C)) - 1;
  return min(max(lo, 0), NG - NWIN);
}

// ===== k_at: wide fused precompute, grid (16, 60) =====
//  y<51 : A[g, bx*256..+256) into LDS, then T5 rows gi=bx*4..+4 (as R10 - verified)
//  y in [51,59): zero msg (128 blocks)
//  y==59: edge histogram into bins + eidx = -1 fill (16 blocks)
__global__ void __launch_bounds__(256) k_at(
    const float* __restrict__ W1, const float* __restrict__ b1,
    const float* __restrict__ W2, const float* __restrict__ b2,
    const float* __restrict__ Wt, const float* __restrict__ dist,
    uint16_t* __restrict__ T5B, float* __restrict__ msg,
    int* __restrict__ bins, int* __restrict__ eidx,
    int n_out, int E, int ne) {
  int g = blockIdx.y, bx = blockIdx.x;
  if (g >= NSLOT) {
    if (g < NSLOT + 8) {                       // zero msg
      int n4 = n_out >> 2;
      float4 z = {0.f, 0.f, 0.f, 0.f};
      for (int t = ((g - NSLOT) * 16 + bx) * 256 + threadIdx.x; t < n4; t += 128 * 256)
        reinterpret_cast<float4*>(msg)[t] = z;
    } else {                                   // histogram + eidx fill
      int tt = bx * 256 + threadIdx.x;         // 0..4095
      for (int e = tt; e < E; e += 4096)
        atomicAdd(&bins[lo_of(dist[e])], 1);
      for (int i = tt; i < ne; i += 4096) eidx[i] = -1;
    }
    return;
  }
  __shared__ float Aloc[256];
  __shared__ float WtL[64 * 65];               // padded: row stride 65
  const int t = threadIdx.x;
  const int ij = bx * 256 + t;

  #pragma unroll
  for (int q = 0; q < 4; ++q) {
    int idx = q * 256 + t;
    float4 v = reinterpret_cast<const float4*>(Wt)[idx];
    int mm = idx >> 4, jj = (idx & 15) * 4;
    float* dst = &WtL[mm * 65 + jj];
    dst[0] = v.x; dst[1] = v.y; dst[2] = v.z; dst[3] = v.w;
  }
  {
    float acc = 0.f;
    if (g < NG) {
      const float* w1r = W1 + g * UNITS;
      #pragma unroll 8
      for (int k = 0; k < UNITS; ++k) acc = fmaf(w1r[k], W2[k * UU + ij], acc);
    } else {
      #pragma unroll 8
      for (int k = 0; k < UNITS; ++k) acc = fmaf(b1[k], W2[k * UU + ij], acc);
      acc += b2[ij];
    }
    Aloc[t] = acc;
  }
  __syncthreads();

  const int i_local = t >> 6, m = t & 63;
  const float* ar = &Aloc[i_local * 64];
  const float* wr = &WtL[m * 65];
  float acc = 0.f;
  #pragma unroll 8
  for (int j = 0; j < UNITS; ++j) acc = fmaf(ar[j], wr[j], acc);
  const int gi = bx * 4 + i_local;
  T5B[(((g << 3) + (m >> 3)) << 9) + (gi << 3) + (m & 7)] = f2bf(acc);
}

// ===== k_scan: bucket bases (16-aligned caps), cursor = base copy =====
__global__ void k_scan(const int* __restrict__ bins, int* __restrict__ base,
                       int* __restrict__ cursor) {
  if (threadIdx.x == 0) {
    int off = 0;
    for (int b = 0; b < NBKT; ++b) {
      base[b] = off; cursor[b] = off;
      off += ((bins[b] + 15) >> 4) << 4;
    }
    base[NBKT] = off;                          // 16*total_tiles
  }
}

// ===== k_scat: scatter edge ids into bucketed, 16-padded eidx =====
__global__ void k_scat(const float* __restrict__ dist, int* __restrict__ cursor,
                       int* __restrict__ eidx, int E) {
  for (int e = blockIdx.x * 256 + threadIdx.x; e < E; e += gridDim.x * 256) {
    int lo = lo_of(dist[e]);
    int pos = atomicAdd(&cursor[lo], 1);
    eidx[pos] = e;
  }
}

// ===== k_em: 16-edge MFMA tiles, Y-free =====
// Wave = one tile. All edges in tile share bucket b (window b..b+3, bias).
// Lane (lr,lg): owns edge lr's meta; A-frag row lr, k = kk*32+lg*8+j.
// B cols permuted (4*lr+nt) as validated in k_y. D: row=edge lg*4+q, ch=4*lr+nt.
__global__ void __launch_bounds__(256) k_em(
    const float* __restrict__ nf, const int* __restrict__ ei,
    const float* __restrict__ dist, const uint16_t* __restrict__ T5B,
    const int* __restrict__ eidx, const int* __restrict__ base,
    float* __restrict__ msg, int E) {
  int w = threadIdx.x >> 6, l = threadIdx.x & 63;
  int lr = l & 15, lg = l >> 4;
  int t16 = (blockIdx.x * 4 + w) * 16;
  int total = base[NBKT];
  if (t16 >= total) return;                    // wave-uniform exit

  int b = 0;
  #pragma unroll
  for (int i = 1; i < NBKT; ++i) b += (t16 >= base[i]);

  int e = eidx[t16 + lr];                      // all lg groups load same 16 ids
  bool valid = (e >= 0);
  int src = valid ? ei[e] : 0;
  int dst = valid ? ei[E + e] : 0;
  float d = valid ? dist[e] : 3.0e30f;         // dummy -> exp(-inf) = 0

  float df[5];
  #pragma unroll
  for (int s = 0; s < NWIN; ++s) {
    float tt = d - (float)(b + s) * STEP_C;
    df[s] = __expf(-GAMMA_C * tt * tt);
  }
  df[NWIN] = valid ? 1.f : 0.f;                // bias slot

  union { bf16x8 v; uint32_t u[4]; } afr[2];
  const float4* ab = reinterpret_cast<const float4*>(nf + src * UNITS) + lg * 2;
  #pragma unroll
  for (int kk = 0; kk < 2; ++kk) {
    float4 v0 = ab[kk * 8], v1 = ab[kk * 8 + 1];
    afr[kk].u[0] = pk_bf16(v0.x, v0.y);
    afr[kk].u[1] = pk_bf16(v0.z, v0.w);
    afr[kk].u[2] = pk_bf16(v1.x, v1.y);
    afr[kk].u[3] = pk_bf16(v1.z, v1.w);
  }

  f32x4 run[4] = {};
  #pragma unroll
  for (int s = 0; s < 5; ++s) {
    int g = (s < NWIN) ? (b + s) : NG;
    const char* bb = (const char*)T5B + (g << 13) + (lg << 10) + (lr << 6);
    f32x4 acc[4] = {};
    #pragma unroll
    for (int kk = 0; kk < 2; ++kk)
      #pragma unroll
      for (int nt = 0; nt < 4; ++nt) {
        bf16x8 bf = *reinterpret_cast<const bf16x8*>(bb + (kk << 12) + (nt << 4));
        acc[nt] = __builtin_amdgcn_mfma_f32_16x16x32_bf16(afr[kk].v, bf, acc[nt], 0, 0, 0);
      }
    float dfq[4];
    #pragma unroll
    for (int q = 0; q < 4; ++q) dfq[q] = __shfl(df[s], lg * 4 + q, 64);
    #pragma unroll
    for (int nt = 0; nt < 4; ++nt)
      #pragma unroll
      for (int q = 0; q < 4; ++q)
        run[nt][q] = fmaf(dfq[q], acc[nt][q], run[nt][q]);
  }

  #pragma unroll
  for (int q = 0; q < 4; ++q) {
    int dq = __shfl(dst, lg * 4 + q, 64);
    #pragma unroll
    for (int nt = 0; nt < 4; ++nt)
      atomicAdd(&msg[dq * UNITS + 4 * lr + nt], run[nt][q]);
  }
}

// out = softplus(msg) - ln(2), numerically stable
__global__ void k_final(const float* __restrict__ msg, float* __restrict__ out, int n) {
  int i = blockIdx.x * 256 + threadIdx.x;
  if (i >= n) return;
  float x = msg[i];
  float sp = (x > 0.f) ? (x + log1pf(__expf(-x))) : log1pf(__expf(x));
  out[i] = sp - 0.69314718056f;
}

extern "C" void kernel_launch(void* const* d_in, const int* in_sizes, int n_in,
                              void* d_out, int out_size, void* d_ws, size_t ws_size,
                              hipStream_t stream) {
  const float* nf   = (const float*)d_in[0];
  const int*   ei   = (const int*)d_in[1];
  const float* dist = (const float*)d_in[2];
  const float* W1   = (const float*)d_in[3];
  const float* b1   = (const float*)d_in[4];
  const float* W2   = (const float*)d_in[5];
  const float* b2   = (const float*)d_in[6];
  const float* Wt   = (const float*)d_in[7];
  float* out = (float*)d_out;

  int E = in_sizes[2];               // 50000
  int n_out = out_size;              // N_NODES * UNITS

  int mt = E / 16 + NBKT + 1;        // max 16-edge tiles (caps round up per bucket)
  int ne = mt * 16;                  // eidx entries

  // workspace layout
  char* ws = (char*)d_ws;
  size_t off_msg  = 417792;                          // T5B: 51*4096*2
  size_t off_bins = off_msg + (size_t)n_out * 4;     // msg
  size_t off_base = off_bins + 64 * 4;               // bins (NBKT, padded)
  size_t off_cur  = off_base + 64 * 4;               // base (NBKT+1, padded)
  size_t off_eidx = off_cur + 64 * 4;                // cursor

  uint16_t* T5B   = (uint16_t*)ws;
  float*    msg   = (float*)(ws + off_msg);
  int*      bins  = (int*)(ws + off_bins);
  int*      base  = (int*)(ws + off_base);
  int*      cursor= (int*)(ws + off_cur);
  int*      eidx  = (int*)(ws + off_eidx);

  hipMemsetAsync(bins, 0, 64 * 4, stream);           // zero bins each replay

  k_at  <<<dim3(16, NSLOT + 9), 256, 0, stream>>>(W1, b1, W2, b2, Wt, dist,
                                                  T5B, msg, bins, eidx, n_out, E, ne);
  k_scan<<<1, 64, 0, stream>>>(bins, base, cursor);
  k_scat<<<64, 256, 0, stream>>>(dist, cursor, eidx, E);
  k_em  <<<(mt + 3) / 4, 256, 0, stream>>>(nf, ei, dist, T5B, eidx, base, msg, E);
  k_final<<<(n_out + 255) / 256, 256, 0, stream>>>(msg, out, n_out);
}

// Round 12
// 191.950 us; speedup vs baseline: 1.3512x; 1.3512x over previous
//
#include <hip/hip_runtime.h>
#include <stdint.h>

#define UNITS 64
#define UU 4096          // UNITS*UNITS
#define NG 50
#define NSLOT 51         // 50 gaussians + 1 bias slot
#define GAMMA_C 10.0f
#define STEP_C (30.0f / 49.0f)
#define NWIN 4           // gaussian window width (centers lo..lo+3)
#define NBKT 47          // lo in [0, 46]

typedef __attribute__((ext_vector_type(8))) short bf16x8;
typedef __attribute__((ext_vector_type(4))) float f32x4;

__device__ __forceinline__ float bfu(uint16_t v) { return __uint_as_float(((uint32_t)v) << 16); }
__device__ __forceinline__ uint16_t f2bf(float x) {
  uint32_t u = __float_as_uint(x);
  u += 0x7fffu + ((u >> 16) & 1u);           // RNE to bf16
  return (uint16_t)(u >> 16);
}
__device__ __forceinline__ uint32_t pk_bf16(float lo, float hi) {
  uint32_t r;
  asm("v_cvt_pk_bf16_f32 %0, %1, %2" : "=v"(r) : "v"(lo), "v"(hi));
  return r;
}
__device__ __forceinline__ int lo_of(float d) {
  int lo = (int)floorf(d * (1.0f / STEP_C)) - 1;
  return min(max(lo, 0), NG - NWIN);
}

// ===== k_at: wide fused precompute, grid (16, 60) =====
//  y<51 : A[g, bx*256..+256) into LDS, then T5 rows gi=bx*4..+4 (R10-verified)
//  y in [51,59): zero msg (128 blocks)
//  y==59: edge histogram into bins + eidx = -1 fill (16 blocks)
__global__ void __launch_bounds__(256) k_at(
    const float* __restrict__ W1, const float* __restrict__ b1,
    const float* __restrict__ W2, const float* __restrict__ b2,
    const float* __restrict__ Wt, const float* __restrict__ dist,
    uint16_t* __restrict__ T5B, float* __restrict__ msg,
    int* __restrict__ bins, int* __restrict__ eidx,
    int n_out, int E, int ne) {
  int g = blockIdx.y, bx = blockIdx.x;
  if (g >= NSLOT) {
    if (g < NSLOT + 8) {                       // zero msg
      int n4 = n_out >> 2;
      float4 z = {0.f, 0.f, 0.f, 0.f};
      for (int t = ((g - NSLOT) * 16 + bx) * 256 + threadIdx.x; t < n4; t += 128 * 256)
        reinterpret_cast<float4*>(msg)[t] = z;
    } else {                                   // histogram + eidx fill
      int tt = bx * 256 + threadIdx.x;         // 0..4095
      for (int e = tt; e < E; e += 4096)
        atomicAdd(&bins[lo_of(dist[e])], 1);
      for (int i = tt; i < ne; i += 4096) eidx[i] = -1;
    }
    return;
  }
  __shared__ float Aloc[256];
  __shared__ float WtL[64 * 65];               // padded: row stride 65
  const int t = threadIdx.x;
  const int ij = bx * 256 + t;

  #pragma unroll
  for (int q = 0; q < 4; ++q) {
    int idx = q * 256 + t;
    float4 v = reinterpret_cast<const float4*>(Wt)[idx];
    int mm = idx >> 4, jj = (idx & 15) * 4;
    float* dst = &WtL[mm * 65 + jj];
    dst[0] = v.x; dst[1] = v.y; dst[2] = v.z; dst[3] = v.w;
  }
  {
    float acc = 0.f;
    if (g < NG) {
      const float* w1r = W1 + g * UNITS;
      #pragma unroll 8
      for (int k = 0; k < UNITS; ++k) acc = fmaf(w1r[k], W2[k * UU + ij], acc);
    } else {
      #pragma unroll 8
      for (int k = 0; k < UNITS; ++k) acc = fmaf(b1[k], W2[k * UU + ij], acc);
      acc += b2[ij];
    }
    Aloc[t] = acc;
  }
  __syncthreads();

  const int i_local = t >> 6, m = t & 63;
  const float* ar = &Aloc[i_local * 64];
  const float* wr = &WtL[m * 65];
  float acc = 0.f;
  #pragma unroll 8
  for (int j = 0; j < UNITS; ++j) acc = fmaf(ar[j], wr[j], acc);
  const int gi = bx * 4 + i_local;
  T5B[(((g << 3) + (m >> 3)) << 9) + (gi << 3) + (m & 7)] = f2bf(acc);
}

// ===== k_scan: bucket bases (16-aligned caps), cursor = base copy =====
__global__ void k_scan(const int* __restrict__ bins, int* __restrict__ base,
                       int* __restrict__ cursor) {
  if (threadIdx.x == 0) {
    int off = 0;
    for (int b = 0; b < NBKT; ++b) {
      base[b] = off; cursor[b] = off;
      off += ((bins[b] + 15) >> 4) << 4;
    }
    base[NBKT] = off;                          // 16*total_tiles
  }
}

// ===== k_scat: scatter edge ids into bucketed, 16-padded eidx =====
__global__ void k_scat(const float* __restrict__ dist, int* __restrict__ cursor,
                       int* __restrict__ eidx, int E) {
  for (int e = blockIdx.x * 256 + threadIdx.x; e < E; e += gridDim.x * 256) {
    int lo = lo_of(dist[e]);
    int pos = atomicAdd(&cursor[lo], 1);
    eidx[pos] = e;
  }
}

// ===== k_em: 16-edge MFMA tiles, Y-free, LDS-transposed COALESCED atomics =====
// Wave = one tile. All edges in tile share bucket b (window b..b+3, bias).
// Lane (lr,lg): edge lr's meta; A-frag row lr, k = kk*32+lg*8+j.
// B cols permuted (4*lr+nt). D: row = edge lg*4+q, ch = 4*lr+nt.
// Transpose 16x64 tile through LDS, then per-row 64-lane coalesced atomicAdd.
__global__ void __launch_bounds__(256) k_em(
    const float* __restrict__ nf, const int* __restrict__ ei,
    const float* __restrict__ dist, const uint16_t* __restrict__ T5B,
    const int* __restrict__ eidx, const int* __restrict__ base,
    float* __restrict__ msg, int E) {
  __shared__ float tile[4][16 * 64];           // 4 KB per wave
  int w = threadIdx.x >> 6, l = threadIdx.x & 63;
  int lr = l & 15, lg = l >> 4;
  int t16 = (blockIdx.x * 4 + w) * 16;
  int total = base[NBKT];
  if (t16 >= total) return;                    // wave-uniform exit (no barriers used)

  int b = 0;
  #pragma unroll
  for (int i = 1; i < NBKT; ++i) b += (t16 >= base[i]);

  int e = eidx[t16 + lr];                      // all lg groups load same 16 ids
  bool valid = (e >= 0);
  int src = valid ? ei[e] : 0;
  int dst = valid ? ei[E + e] : -1;            // -1 marks dummy row (skip atomic)
  float d = valid ? dist[e] : 3.0e30f;         // dummy -> df == 0

  float df[5];
  #pragma unroll
  for (int s = 0; s < NWIN; ++s) {
    float tt = d - (float)(b + s) * STEP_C;
    df[s] = __expf(-GAMMA_C * tt * tt);
  }
  df[NWIN] = valid ? 1.f : 0.f;                // bias slot

  union { bf16x8 v; uint32_t u[4]; } afr[2];
  const float4* ab = reinterpret_cast<const float4*>(nf + src * UNITS) + lg * 2;
  #pragma unroll
  for (int kk = 0; kk < 2; ++kk) {
    float4 v0 = ab[kk * 8], v1 = ab[kk * 8 + 1];
    afr[kk].u[0] = pk_bf16(v0.x, v0.y);
    afr[kk].u[1] = pk_bf16(v0.z, v0.w);
    afr[kk].u[2] = pk_bf16(v1.x, v1.y);
    afr[kk].u[3] = pk_bf16(v1.z, v1.w);
  }

  f32x4 run[4] = {};
  #pragma unroll
  for (int s = 0; s < 5; ++s) {
    int g = (s < NWIN) ? (b + s) : NG;
    const char* bb = (const char*)T5B + (g << 13) + (lg << 10) + (lr << 6);
    f32x4 acc[4] = {};
    #pragma unroll
    for (int kk = 0; kk < 2; ++kk)
      #pragma unroll
      for (int nt = 0; nt < 4; ++nt) {
        bf16x8 bf = *reinterpret_cast<const bf16x8*>(bb + (kk << 12) + (nt << 4));
        acc[nt] = __builtin_amdgcn_mfma_f32_16x16x32_bf16(afr[kk].v, bf, acc[nt], 0, 0, 0);
      }
    float dfq[4];
    #pragma unroll
    for (int q = 0; q < 4; ++q) dfq[q] = __shfl(df[s], lg * 4 + q, 64);
    #pragma unroll
    for (int nt = 0; nt < 4; ++nt)
      #pragma unroll
      for (int q = 0; q < 4; ++q)
        run[nt][q] = fmaf(dfq[q], acc[nt][q], run[nt][q]);
  }

  // transpose through per-wave LDS: lane writes its 4 contiguous channels per row
  float* tw = tile[w];
  #pragma unroll
  for (int q = 0; q < 4; ++q) {
    float4 v4 = {run[0][q], run[1][q], run[2][q], run[3][q]};
    *reinterpret_cast<float4*>(&tw[(lg * 4 + q) * 64 + 4 * lr]) = v4;
  }
  asm volatile("" ::: "memory");               // keep issue order; same-wave DS ops are in-order

  // coalesced atomics: row r -> 64 lanes contiguous (full sectors, payload-sized traffic)
  #pragma unroll
  for (int r = 0; r < 16; ++r) {
    int dr = __shfl(dst, r, 64);               // lane r holds edge r's dst
    if (dr < 0) continue;                      // wave-uniform skip for dummy rows
    atomicAdd(&msg[dr * UNITS + l], tw[r * 64 + l]);
  }
}

// out = softplus(msg) - ln(2), numerically stable
__global__ void k_final(const float* __restrict__ msg, float* __restrict__ out, int n) {
  int i = blockIdx.x * 256 + threadIdx.x;
  if (i >= n) return;
  float x = msg[i];
  float sp = (x > 0.f) ? (x + log1pf(__expf(-x))) : log1pf(__expf(x));
  out[i] = sp - 0.69314718056f;
}

extern "C" void kernel_launch(void* const* d_in, const int* in_sizes, int n_in,
                              void* d_out, int out_size, void* d_ws, size_t ws_size,
                              hipStream_t stream) {
  const float* nf   = (const float*)d_in[0];
  const int*   ei   = (const int*)d_in[1];
  const float* dist = (const float*)d_in[2];
  const float* W1   = (const float*)d_in[3];
  const float* b1   = (const float*)d_in[4];
  const float* W2   = (const float*)d_in[5];
  const float* b2   = (const float*)d_in[6];
  const float* Wt   = (const float*)d_in[7];
  float* out = (float*)d_out;

  int E = in_sizes[2];               // 50000
  int n_out = out_size;              // N_NODES * UNITS

  int mt = E / 16 + NBKT + 1;        // max 16-edge tiles (caps round up per bucket)
  int ne = mt * 16;                  // eidx entries

  // workspace layout
  char* ws = (char*)d_ws;
  size_t off_msg  = 417792;                          // T5B: 51*4096*2
  size_t off_bins = off_msg + (size_t)n_out * 4;     // msg
  size_t off_base = off_bins + 64 * 4;               // bins (NBKT, padded)
  size_t off_cur  = off_base + 64 * 4;               // base (NBKT+1, padded)
  size_t off_eidx = off_cur + 64 * 4;                // cursor

  uint16_t* T5B   = (uint16_t*)ws;
  float*    msg   = (float*)(ws + off_msg);
  int*      bins  = (int*)(ws + off_bins);
  int*      base  = (int*)(ws + off_base);
  int*      cursor= (int*)(ws + off_cur);
  int*      eidx  = (int*)(ws + off_eidx);

  hipMemsetAsync(bins, 0, 64 * 4, stream);           // zero bins each replay

  k_at  <<<dim3(16, NSLOT + 9), 256, 0, stream>>>(W1, b1, W2, b2, Wt, dist,
                                                  T5B, msg, bins, eidx, n_out, E, ne);
  k_scan<<<1, 64, 0, stream>>>(bins, base, cursor);
  k_scat<<<64, 256, 0, stream>>>(dist, cursor, eidx, E);
  k_em  <<<(mt + 3) / 4, 256, 0, stream>>>(nf, ei, dist, T5B, eidx, base, msg, E);
  k_final<<<(n_out + 255) / 256, 256, 0, stream>>>(msg, out, n_out);
}

// Round 13
// 48.202 us; speedup vs baseline: 5.3806x; 3.9822x over previous
//
#include <hip/hip_runtime.h>
#include <stdint.h>

#define UNITS 64
#define UU 4096          // UNITS*UNITS
#define NG 50
#define NSLOT 51         // 50 gaussians + 1 bias slot
#define GAMMA_C 10.0f
#define STEP_C (30.0f / 49.0f)
#define NWIN 4           // gaussian window width (centers lo..lo+3)
#define NBKT 47          // lo in [0, 46]

typedef __attribute__((ext_vector_type(8))) short bf16x8;
typedef __attribute__((ext_vector_type(4))) float f32x4;

__device__ __forceinline__ float bfu(uint16_t v) { return __uint_as_float(((uint32_t)v) << 16); }
__device__ __forceinline__ uint16_t f2bf(float x) {
  uint32_t u = __float_as_uint(x);
  u += 0x7fffu + ((u >> 16) & 1u);           // RNE to bf16
  return (uint16_t)(u >> 16);
}
__device__ __forceinline__ uint32_t pk_bf16(float lo, float hi) {
  uint32_t r;
  asm("v_cvt_pk_bf16_f32 %0, %1, %2" : "=v"(r) : "v"(lo), "v"(hi));
  return r;
}
__device__ __forceinline__ int lo_of(float d) {
  int lo = (int)floorf(d * (1.0f / STEP_C)) - 1;
  return min(max(lo, 0), NG - NWIN);
}

// ===== k_at: wide fused precompute, grid (16, 60) =====
//  y<51 : A[g, bx*256..+256) into LDS, then T5 rows gi=bx*4..+4 (R10-verified)
//  y in [51,59): zero msg (128 blocks)
//  y==59: LDS-privatized edge histogram (+eidx=-1 fill): <=47 global atomics/block
__global__ void __launch_bounds__(256) k_at(
    const float* __restrict__ W1, const float* __restrict__ b1,
    const float* __restrict__ W2, const float* __restrict__ b2,
    const float* __restrict__ Wt, const float* __restrict__ dist,
    uint16_t* __restrict__ T5B, float* __restrict__ msg,
    int* __restrict__ bins, int* __restrict__ eidx,
    int n_out, int E, int ne) {
  int g = blockIdx.y, bx = blockIdx.x;
  if (g >= NSLOT) {
    if (g < NSLOT + 8) {                       // zero msg
      int n4 = n_out >> 2;
      float4 z = {0.f, 0.f, 0.f, 0.f};
      for (int t = ((g - NSLOT) * 16 + bx) * 256 + threadIdx.x; t < n4; t += 128 * 256)
        reinterpret_cast<float4*>(msg)[t] = z;
    } else {                                   // histogram (LDS-privatized) + eidx fill
      __shared__ int hloc[NBKT];
      for (int i = threadIdx.x; i < NBKT; i += 256) hloc[i] = 0;
      __syncthreads();
      int tt = bx * 256 + threadIdx.x;         // 0..4095
      for (int e = tt; e < E; e += 4096)
        atomicAdd(&hloc[lo_of(dist[e])], 1);   // LDS atomic: banked, fast
      __syncthreads();
      for (int i = threadIdx.x; i < NBKT; i += 256)
        if (hloc[i]) atomicAdd(&bins[i], hloc[i]);  // <=47 global RMW per block
      for (int i = tt; i < ne; i += 4096) eidx[i] = -1;
    }
    return;
  }
  __shared__ float Aloc[256];
  __shared__ float WtL[64 * 65];               // padded: row stride 65
  const int t = threadIdx.x;
  const int ij = bx * 256 + t;

  #pragma unroll
  for (int q = 0; q < 4; ++q) {
    int idx = q * 256 + t;
    float4 v = reinterpret_cast<const float4*>(Wt)[idx];
    int mm = idx >> 4, jj = (idx & 15) * 4;
    float* dst = &WtL[mm * 65 + jj];
    dst[0] = v.x; dst[1] = v.y; dst[2] = v.z; dst[3] = v.w;
  }
  {
    float acc = 0.f;
    if (g < NG) {
      const float* w1r = W1 + g * UNITS;
      #pragma unroll 8
      for (int k = 0; k < UNITS; ++k) acc = fmaf(w1r[k], W2[k * UU + ij], acc);
    } else {
      #pragma unroll 8
      for (int k = 0; k < UNITS; ++k) acc = fmaf(b1[k], W2[k * UU + ij], acc);
      acc += b2[ij];
    }
    Aloc[t] = acc;
  }
  __syncthreads();

  const int i_local = t >> 6, m = t & 63;
  const float* ar = &Aloc[i_local * 64];
  const float* wr = &WtL[m * 65];
  float acc = 0.f;
  #pragma unroll 8
  for (int j = 0; j < UNITS; ++j) acc = fmaf(ar[j], wr[j], acc);
  const int gi = bx * 4 + i_local;
  T5B[(((g << 3) + (m >> 3)) << 9) + (gi << 3) + (m & 7)] = f2bf(acc);
}

// ===== k_scan: one-wave shfl prefix scan of 16-aligned bucket caps =====
__global__ void k_scan(const int* __restrict__ bins, int* __restrict__ base,
                       int* __restrict__ cursor) {
  int l = threadIdx.x;                         // 64 threads
  int v = (l < NBKT) ? ((bins[l] + 15) >> 4) << 4 : 0;
  int inc = v;
  #pragma unroll
  for (int s = 1; s < 64; s <<= 1) {
    int t = __shfl_up(inc, s, 64);
    if (l >= s) inc += t;
  }
  int exc = inc - v;                           // exclusive prefix
  if (l < NBKT) { base[l] = exc; cursor[l] = exc; }
  if (l == NBKT) base[NBKT] = exc;             // total (v==0 at this lane)
}

// ===== k_scat: LDS-privatized bucket scatter =====
// Per block: local histogram -> one global atomicAdd per non-empty bin to
// reserve a range -> place edges via LDS cursors. <=47 global RMW per block.
__global__ void __launch_bounds__(256) k_scat(const float* __restrict__ dist,
                                              int* __restrict__ cursor,
                                              int* __restrict__ eidx, int E) {
  __shared__ int hcnt[NBKT], hbase[NBKT], hcur[NBKT];
  int per = (E + gridDim.x - 1) / gridDim.x;
  int e0 = blockIdx.x * per, e1 = min(e0 + per, E);
  for (int i = threadIdx.x; i < NBKT; i += 256) { hcnt[i] = 0; hcur[i] = 0; }
  __syncthreads();
  for (int e = e0 + threadIdx.x; e < e1; e += 256)
    atomicAdd(&hcnt[lo_of(dist[e])], 1);       // LDS atomic
  __syncthreads();
  for (int i = threadIdx.x; i < NBKT; i += 256)
    hbase[i] = hcnt[i] ? atomicAdd(&cursor[i], hcnt[i]) : 0;
  __syncthreads();
  for (int e = e0 + threadIdx.x; e < e1; e += 256) {
    int b = lo_of(dist[e]);
    int p = hbase[b] + atomicAdd(&hcur[b], 1); // LDS cursor
    eidx[p] = e;
  }
}

// ===== k_em: 16-edge MFMA tiles, Y-free, LDS-transposed COALESCED atomics =====
// (unchanged from R12 - WRITE_SIZE fix verified)
__global__ void __launch_bounds__(256) k_em(
    const float* __restrict__ nf, const int* __restrict__ ei,
    const float* __restrict__ dist, const uint16_t* __restrict__ T5B,
    const int* __restrict__ eidx, const int* __restrict__ base,
    float* __restrict__ msg, int E) {
  __shared__ float tile[4][16 * 64];           // 4 KB per wave
  int w = threadIdx.x >> 6, l = threadIdx.x & 63;
  int lr = l & 15, lg = l >> 4;
  int t16 = (blockIdx.x * 4 + w) * 16;
  int total = base[NBKT];
  if (t16 >= total) return;                    // wave-uniform exit (no barriers used)

  int b = 0;
  #pragma unroll
  for (int i = 1; i < NBKT; ++i) b += (t16 >= base[i]);

  int e = eidx[t16 + lr];                      // all lg groups load same 16 ids
  bool valid = (e >= 0);
  int src = valid ? ei[e] : 0;
  int dst = valid ? ei[E + e] : -1;            // -1 marks dummy row (skip atomic)
  float d = valid ? dist[e] : 3.0e30f;         // dummy -> df == 0

  float df[5];
  #pragma unroll
  for (int s = 0; s < NWIN; ++s) {
    float tt = d - (float)(b + s) * STEP_C;
    df[s] = __expf(-GAMMA_C * tt * tt);
  }
  df[NWIN] = valid ? 1.f : 0.f;                // bias slot

  union { bf16x8 v; uint32_t u[4]; } afr[2];
  const float4* ab = reinterpret_cast<const float4*>(nf + src * UNITS) + lg * 2;
  #pragma unroll
  for (int kk = 0; kk < 2; ++kk) {
    float4 v0 = ab[kk * 8], v1 = ab[kk * 8 + 1];
    afr[kk].u[0] = pk_bf16(v0.x, v0.y);
    afr[kk].u[1] = pk_bf16(v0.z, v0.w);
    afr[kk].u[2] = pk_bf16(v1.x, v1.y);
    afr[kk].u[3] = pk_bf16(v1.z, v1.w);
  }

  f32x4 run[4] = {};
  #pragma unroll
  for (int s = 0; s < 5; ++s) {
    int g = (s < NWIN) ? (b + s) : NG;
    const char* bb = (const char*)T5B + (g << 13) + (lg << 10) + (lr << 6);
    f32x4 acc[4] = {};
    #pragma unroll
    for (int kk = 0; kk < 2; ++kk)
      #pragma unroll
      for (int nt = 0; nt < 4; ++nt) {
        bf16x8 bf = *reinterpret_cast<const bf16x8*>(bb + (kk << 12) + (nt << 4));
        acc[nt] = __builtin_amdgcn_mfma_f32_16x16x32_bf16(afr[kk].v, bf, acc[nt], 0, 0, 0);
      }
    float dfq[4];
    #pragma unroll
    for (int q = 0; q < 4; ++q) dfq[q] = __shfl(df[s], lg * 4 + q, 64);
    #pragma unroll
    for (int nt = 0; nt < 4; ++nt)
      #pragma unroll
      for (int q = 0; q < 4; ++q)
        run[nt][q] = fmaf(dfq[q], acc[nt][q], run[nt][q]);
  }

  // transpose through per-wave LDS: lane writes its 4 contiguous channels per row
  float* tw = tile[w];
  #pragma unroll
  for (int q = 0; q < 4; ++q) {
    float4 v4 = {run[0][q], run[1][q], run[2][q], run[3][q]};
    *reinterpret_cast<float4*>(&tw[(lg * 4 + q) * 64 + 4 * lr]) = v4;
  }
  asm volatile("" ::: "memory");               // keep issue order; same-wave DS ops are in-order

  // coalesced atomics: row r -> 64 lanes contiguous (full sectors, payload-sized traffic)
  #pragma unroll
  for (int r = 0; r < 16; ++r) {
    int dr = __shfl(dst, r, 64);               // lane r holds edge r's dst
    if (dr < 0) continue;                      // wave-uniform skip for dummy rows
    atomicAdd(&msg[dr * UNITS + l], tw[r * 64 + l]);
  }
}

// out = softplus(msg) - ln(2), numerically stable
__global__ void k_final(const float* __restrict__ msg, float* __restrict__ out, int n) {
  int i = blockIdx.x * 256 + threadIdx.x;
  if (i >= n) return;
  float x = msg[i];
  float sp = (x > 0.f) ? (x + log1pf(__expf(-x))) : log1pf(__expf(x));
  out[i] = sp - 0.69314718056f;
}

extern "C" void kernel_launch(void* const* d_in, const int* in_sizes, int n_in,
                              void* d_out, int out_size, void* d_ws, size_t ws_size,
                              hipStream_t stream) {
  const float* nf   = (const float*)d_in[0];
  const int*   ei   = (const int*)d_in[1];
  const float* dist = (const float*)d_in[2];
  const float* W1   = (const float*)d_in[3];
  const float* b1   = (const float*)d_in[4];
  const float* W2   = (const float*)d_in[5];
  const float* b2   = (const float*)d_in[6];
  const float* Wt   = (const float*)d_in[7];
  float* out = (float*)d_out;

  int E = in_sizes[2];               // 50000
  int n_out = out_size;              // N_NODES * UNITS

  int mt = E / 16 + NBKT + 1;        // max 16-edge tiles (caps round up per bucket)
  int ne = mt * 16;                  // eidx entries

  // workspace layout
  char* ws = (char*)d_ws;
  size_t off_msg  = 417792;                          // T5B: 51*4096*2
  size_t off_bins = off_msg + (size_t)n_out * 4;     // msg
  size_t off_base = off_bins + 64 * 4;               // bins (NBKT, padded)
  size_t off_cur  = off_base + 64 * 4;               // base (NBKT+1, padded)
  size_t off_eidx = off_cur + 64 * 4;                // cursor

  uint16_t* T5B   = (uint16_t*)ws;
  float*    msg   = (float*)(ws + off_msg);
  int*      bins  = (int*)(ws + off_bins);
  int*      base  = (int*)(ws + off_base);
  int*      cursor= (int*)(ws + off_cur);
  int*      eidx  = (int*)(ws + off_eidx);

  hipMemsetAsync(bins, 0, 64 * 4, stream);           // zero bins each replay

  k_at  <<<dim3(16, NSLOT + 9), 256, 0, stream>>>(W1, b1, W2, b2, Wt, dist,
                                                  T5B, msg, bins, eidx, n_out, E, ne);
  k_scan<<<1, 64, 0, stream>>>(bins, base, cursor);
  k_scat<<<64, 256, 0, stream>>>(dist, cursor, eidx, E);
  k_em  <<<(mt + 3) / 4, 256, 0, stream>>>(nf, ei, dist, T5B, eidx, base, msg, E);
  k_final<<<(n_out + 255) / 256, 256, 0, stream>>>(msg, out, n_out);
}